// Round 2
// baseline (260.359 us; speedup 1.0000x reference)
//
#include <hip/hip_runtime.h>
#include <hip/hip_bf16.h>

#define KCB 512
#define DF  16
#define BATCH 64

// ---------------------------------------------------------------------------
// 3x3 same-padded conv + bias + relu, NCHW, stride 1.
// Grid: (W/16, H/16, B). Block: 256 threads = 16x16 spatial tile.
// Each thread computes one output pixel for all COUT channels.
// Weights are read with block-uniform indices -> scalar (SGPR) loads.
// ---------------------------------------------------------------------------
template<int CIN, int COUT>
__global__ __launch_bounds__(256) void conv3x3_relu_kernel(
    const float* __restrict__ in, const float* __restrict__ wgt,
    const float* __restrict__ bias, float* __restrict__ out,
    int H, int W)
{
    __shared__ float s_in[CIN][18][18];
    const int b  = blockIdx.z;
    const int x0 = blockIdx.x * 16;
    const int y0 = blockIdx.y * 16;
    const int tid = threadIdx.x;
    const int tx = tid & 15;
    const int ty = tid >> 4;

    // Load input tile with 1-px halo (zero padded at image borders).
    for (int c = 0; c < CIN; ++c) {
        for (int i = tid; i < 18 * 18; i += 256) {
            int iy = i / 18, ix = i % 18;
            int gy = y0 + iy - 1, gx = x0 + ix - 1;
            float v = 0.f;
            if (gy >= 0 && gy < H && gx >= 0 && gx < W)
                v = in[((b * CIN + c) * H + gy) * W + gx];
            s_in[c][iy][ix] = v;
        }
    }
    __syncthreads();

    float acc[COUT];
#pragma unroll
    for (int o = 0; o < COUT; ++o) acc[o] = bias[o];

#pragma unroll
    for (int c = 0; c < CIN; ++c) {
#pragma unroll
        for (int ky = 0; ky < 3; ++ky) {
#pragma unroll
            for (int kx = 0; kx < 3; ++kx) {
                float v = s_in[c][ty + ky][tx + kx];
#pragma unroll
                for (int o = 0; o < COUT; ++o)
                    acc[o] = fmaf(v, wgt[((o * CIN + c) * 3 + ky) * 3 + kx], acc[o]);
            }
        }
    }

    const int gy = y0 + ty, gx = x0 + tx;
#pragma unroll
    for (int o = 0; o < COUT; ++o)
        out[((b * COUT + o) * H + gy) * W + gx] = fmaxf(acc[o], 0.f);
}

// ---------------------------------------------------------------------------
// 2x2 max pool, stride 2 (NCHW). One thread per output element.
// ---------------------------------------------------------------------------
__global__ __launch_bounds__(256) void maxpool2_kernel(
    const float* __restrict__ in, float* __restrict__ out,
    int H, int W, int total)
{
    int idx = blockIdx.x * 256 + threadIdx.x;
    if (idx >= total) return;
    const int OW = W >> 1;
    const int OH = H >> 1;
    int ow = idx % OW;
    int rest = idx / OW;
    int oh = rest % OH;
    int bc = rest / OH;
    const float* p = in + ((size_t)bc * H + oh * 2) * W + ow * 2;
    float m = fmaxf(fmaxf(p[0], p[1]), fmaxf(p[W], p[W + 1]));
    out[idx] = m;
}

// ---------------------------------------------------------------------------
// BoF RBF soft-assignment + L1-normalize over K + partial mean over pixels.
// h: (B, 16, 1024) conv4 output. Grid: (CHUNKS=8, B). Block: 512 threads,
// one per codebook entry. Each block handles 128 pixels.
// partial: (B, CHUNKS, 512) deterministic partial sums.
// ---------------------------------------------------------------------------
__global__ __launch_bounds__(512) void bof_kernel(
    const float* __restrict__ h, const float* __restrict__ codebook,
    const float* __restrict__ sigma, float* __restrict__ partial)
{
    const int PIX = 128;
    const int b = blockIdx.y;
    const int chunk = blockIdx.x;
    const int k = threadIdx.x;

    __shared__ float s_f[DF][PIX];
    __shared__ float s_red[2][8];

    float cb[DF];
#pragma unroll
    for (int d = 0; d < DF; ++d) cb[d] = codebook[k * DF + d];
    const float sg = sigma[k];

    // Stage this chunk's features: s_f[d][j] = h[b, d, n0+j]
    const int n0 = chunk * PIX;
    for (int i = threadIdx.x; i < DF * PIX; i += 512) {
        int d = i >> 7, j = i & (PIX - 1);
        s_f[d][j] = h[((size_t)b * DF + d) * 1024 + n0 + j];
    }
    __syncthreads();

    float acc = 0.f;
    for (int j = 0; j < PIX; ++j) {
        float dist = 0.f;
#pragma unroll
        for (int d = 0; d < DF; ++d) {
            float t = s_f[d][j] - cb[d];
            dist = fmaf(t, t, dist);
        }
        float e = __expf(-dist * sg);

        // block-wide sum over 512 threads (wave reduce + cross-wave LDS)
        float s = e;
#pragma unroll
        for (int off = 32; off > 0; off >>= 1) s += __shfl_xor(s, off);
        if ((threadIdx.x & 63) == 0) s_red[j & 1][threadIdx.x >> 6] = s;
        __syncthreads();
        float denom = 0.f;
#pragma unroll
        for (int wv = 0; wv < 8; ++wv) denom += s_red[j & 1][wv];
        acc += e / fmaxf(denom, 1e-12f);
        // no trailing barrier needed: next iteration writes the OTHER s_red
        // buffer, and the barrier above orders iter j reads vs iter j+2 writes.
    }
    partial[((size_t)b * gridDim.x + chunk) * KCB + k] = acc;
}

// ---------------------------------------------------------------------------
// pooled[b][k] = mean over all pixels = sum(partial) / 1024
// ---------------------------------------------------------------------------
__global__ __launch_bounds__(512) void pool_reduce_kernel(
    const float* __restrict__ partial, float* __restrict__ pooled, int chunks)
{
    int b = blockIdx.x;
    int k = threadIdx.x;
    float s = 0.f;
    for (int c = 0; c < chunks; ++c)
        s += partial[((size_t)b * chunks + c) * KCB + k];
    pooled[b * KCB + k] = s * (1.0f / 1024.0f);
}

// ---------------------------------------------------------------------------
// MLP head: z = relu(pooled @ l1_w^T + l1_b); out = z @ l2_w^T + l2_b
// Grid: B blocks, 64 threads.
// ---------------------------------------------------------------------------
__global__ __launch_bounds__(64) void head_kernel(
    const float* __restrict__ pooled,
    const float* __restrict__ l1w, const float* __restrict__ l1b,
    const float* __restrict__ l2w, const float* __restrict__ l2b,
    float* __restrict__ out)
{
    int b = blockIdx.x;
    int t = threadIdx.x;
    __shared__ float s_z[20];
    if (t < 20) {
        float s = l1b[t];
        const float* pr = pooled + (size_t)b * KCB;
        const float* wr = l1w + (size_t)t * KCB;
        for (int i = 0; i < KCB; ++i) s = fmaf(pr[i], wr[i], s);
        s_z[t] = fmaxf(s, 0.f);
    }
    __syncthreads();
    if (t < 10) {
        float s = l2b[t];
#pragma unroll
        for (int j = 0; j < 20; ++j) s = fmaf(s_z[j], l2w[t * 20 + j], s);
        out[b * 10 + t] = s;
    }
}

// ---------------------------------------------------------------------------
extern "C" void kernel_launch(void* const* d_in, const int* in_sizes, int n_in,
                              void* d_out, int out_size, void* d_ws, size_t ws_size,
                              hipStream_t stream)
{
    const float* x        = (const float*)d_in[0];
    const float* w1       = (const float*)d_in[1];
    const float* b1       = (const float*)d_in[2];
    const float* w2       = (const float*)d_in[3];
    const float* b2       = (const float*)d_in[4];
    const float* w3       = (const float*)d_in[5];
    const float* b3       = (const float*)d_in[6];
    const float* w4       = (const float*)d_in[7];
    const float* b4       = (const float*)d_in[8];
    const float* codebook = (const float*)d_in[9];
    const float* sigma    = (const float*)d_in[10];
    const float* l1w      = (const float*)d_in[11];
    const float* l1b      = (const float*)d_in[12];
    const float* l2w      = (const float*)d_in[13];
    const float* l2b      = (const float*)d_in[14];
    float* out = (float*)d_out;

    // workspace layout (floats)
    float* ws = (float*)d_ws;
    const size_t N_C1 = (size_t)BATCH * 16 * 64 * 64;  // 4,194,304
    const size_t N_C2 = N_C1;
    const size_t N_P  = (size_t)BATCH * 16 * 32 * 32;  // 1,048,576
    const size_t N_C3 = (size_t)BATCH * 24 * 32 * 32;  // 1,572,864
    const size_t N_C4 = N_P;
    const int CHUNKS = 8;
    const size_t N_PART = (size_t)BATCH * CHUNKS * KCB;
    const size_t N_POOL = (size_t)BATCH * KCB;

    float* c1     = ws;                 ws += N_C1;
    float* c2     = ws;                 ws += N_C2;
    float* p      = ws;                 ws += N_P;
    float* c3     = ws;                 ws += N_C3;
    float* c4     = ws;                 ws += N_C4;
    float* part   = ws;                 ws += N_PART;
    float* pooled = ws;                 ws += N_POOL;

    // conv1: (B,3,64,64) -> (B,16,64,64)
    conv3x3_relu_kernel<3, 16><<<dim3(4, 4, BATCH), 256, 0, stream>>>(x, w1, b1, c1, 64, 64);
    // conv2: (B,16,64,64) -> (B,16,64,64)
    conv3x3_relu_kernel<16, 16><<<dim3(4, 4, BATCH), 256, 0, stream>>>(c1, w2, b2, c2, 64, 64);
    // maxpool: (B,16,64,64) -> (B,16,32,32)
    {
        int total = (int)N_P;
        maxpool2_kernel<<<(total + 255) / 256, 256, 0, stream>>>(c2, p, 64, 64, total);
    }
    // conv3: (B,16,32,32) -> (B,24,32,32)
    conv3x3_relu_kernel<16, 24><<<dim3(2, 2, BATCH), 256, 0, stream>>>(p, w3, b3, c3, 32, 32);
    // conv4: (B,24,32,32) -> (B,16,32,32)
    conv3x3_relu_kernel<24, 16><<<dim3(2, 2, BATCH), 256, 0, stream>>>(c3, w4, b4, c4, 32, 32);
    // BoF membership + partial pooling
    bof_kernel<<<dim3(CHUNKS, BATCH), 512, 0, stream>>>(c4, codebook, sigma, part);
    pool_reduce_kernel<<<BATCH, KCB, 0, stream>>>(part, pooled, CHUNKS);
    // MLP head
    head_kernel<<<BATCH, 64, 0, stream>>>(pooled, l1w, l1b, l2w, l2b, out);
}

// Round 3
// 248.880 us; speedup vs baseline: 1.0461x; 1.0461x over previous
//
#include <hip/hip_runtime.h>
#include <hip/hip_bf16.h>

#define KCB 512
#define DF  16
#define BATCH 64

// ---------------------------------------------------------------------------
// Generic 3x3 same conv + bias + relu, NCHW. COUT_T channels per block,
// NG channel-groups (blockIdx.z = b*NG + g). Each thread = one pixel.
// ---------------------------------------------------------------------------
template<int CIN, int COUT_T, int COUT_TOTAL, int NG>
__global__ __launch_bounds__(256) void conv3x3_relu_kernel(
    const float* __restrict__ in, const float* __restrict__ wgt,
    const float* __restrict__ bias, float* __restrict__ out,
    int H, int W)
{
    __shared__ float s_in[CIN][18][18];
    const int zb = blockIdx.z;
    const int b  = zb / NG;
    const int og = (zb % NG) * COUT_T;
    const int x0 = blockIdx.x * 16;
    const int y0 = blockIdx.y * 16;
    const int tid = threadIdx.x;
    const int tx = tid & 15;
    const int ty = tid >> 4;

    for (int c = 0; c < CIN; ++c) {
        for (int i = tid; i < 18 * 18; i += 256) {
            int iy = i / 18, ix = i % 18;
            int gy = y0 + iy - 1, gx = x0 + ix - 1;
            float v = 0.f;
            if (gy >= 0 && gy < H && gx >= 0 && gx < W)
                v = in[((b * CIN + c) * H + gy) * W + gx];
            s_in[c][iy][ix] = v;
        }
    }
    __syncthreads();

    float acc[COUT_T];
#pragma unroll
    for (int o = 0; o < COUT_T; ++o) acc[o] = bias[og + o];

#pragma unroll
    for (int c = 0; c < CIN; ++c) {
#pragma unroll
        for (int ky = 0; ky < 3; ++ky) {
#pragma unroll
            for (int kx = 0; kx < 3; ++kx) {
                float v = s_in[c][ty + ky][tx + kx];
#pragma unroll
                for (int o = 0; o < COUT_T; ++o)
                    acc[o] = fmaf(v, wgt[(((og + o) * CIN + c) * 3 + ky) * 3 + kx], acc[o]);
            }
        }
    }

    const int gy = y0 + ty, gx = x0 + tx;
#pragma unroll
    for (int o = 0; o < COUT_T; ++o)
        out[((b * COUT_TOTAL + og + o) * H + gy) * W + gx] = fmaxf(acc[o], 0.f);
}

// ---------------------------------------------------------------------------
// conv2 (16->16, 64x64) fused with 2x2 maxpool: writes pooled (B,16,32,32).
// 2x2 max via shfl_xor(1) [tx pair] and shfl_xor(16) [ty pair] in-wave.
// ---------------------------------------------------------------------------
__global__ __launch_bounds__(256) void conv2_pool_kernel(
    const float* __restrict__ in, const float* __restrict__ wgt,
    const float* __restrict__ bias, float* __restrict__ out)
{
    const int CIN = 16, COUT = 16, H = 64, W = 64;
    __shared__ float s_in[16][18][18];
    const int b  = blockIdx.z;
    const int x0 = blockIdx.x * 16;
    const int y0 = blockIdx.y * 16;
    const int tid = threadIdx.x;
    const int tx = tid & 15;
    const int ty = tid >> 4;

    for (int c = 0; c < CIN; ++c) {
        for (int i = tid; i < 18 * 18; i += 256) {
            int iy = i / 18, ix = i % 18;
            int gy = y0 + iy - 1, gx = x0 + ix - 1;
            float v = 0.f;
            if (gy >= 0 && gy < H && gx >= 0 && gx < W)
                v = in[((b * CIN + c) * H + gy) * W + gx];
            s_in[c][iy][ix] = v;
        }
    }
    __syncthreads();

    float acc[COUT];
#pragma unroll
    for (int o = 0; o < COUT; ++o) acc[o] = bias[o];

#pragma unroll
    for (int c = 0; c < CIN; ++c) {
#pragma unroll
        for (int ky = 0; ky < 3; ++ky) {
#pragma unroll
            for (int kx = 0; kx < 3; ++kx) {
                float v = s_in[c][ty + ky][tx + kx];
#pragma unroll
                for (int o = 0; o < COUT; ++o)
                    acc[o] = fmaf(v, wgt[((o * CIN + c) * 3 + ky) * 3 + kx], acc[o]);
            }
        }
    }

    const bool writer = ((tx & 1) == 0) && ((ty & 1) == 0);
    const int px = (x0 + tx) >> 1;
    const int py = (y0 + ty) >> 1;
#pragma unroll
    for (int o = 0; o < COUT; ++o) {
        float r = fmaxf(acc[o], 0.f);
        r = fmaxf(r, __shfl_xor(r, 1));   // tx pair
        r = fmaxf(r, __shfl_xor(r, 16));  // ty pair (same wave: ty block of 4)
        if (writer)
            out[((b * COUT + o) * 32 + py) * 32 + px] = r;
    }
}

// ---------------------------------------------------------------------------
// conv4 (24->16, 32x32): writes transposed features ft (B, 1024, 16) and
// squared norms f2 (B, 1024). No NCHW output needed (bof is sole consumer).
// ---------------------------------------------------------------------------
__global__ __launch_bounds__(256) void conv4_ft_kernel(
    const float* __restrict__ in, const float* __restrict__ wgt,
    const float* __restrict__ bias, float* __restrict__ ft,
    float* __restrict__ f2)
{
    const int CIN = 24, COUT = 16, H = 32, W = 32;
    __shared__ float s_in[24][18][18];
    const int b  = blockIdx.z;
    const int x0 = blockIdx.x * 16;
    const int y0 = blockIdx.y * 16;
    const int tid = threadIdx.x;
    const int tx = tid & 15;
    const int ty = tid >> 4;

    for (int c = 0; c < CIN; ++c) {
        for (int i = tid; i < 18 * 18; i += 256) {
            int iy = i / 18, ix = i % 18;
            int gy = y0 + iy - 1, gx = x0 + ix - 1;
            float v = 0.f;
            if (gy >= 0 && gy < H && gx >= 0 && gx < W)
                v = in[((b * CIN + c) * H + gy) * W + gx];
            s_in[c][iy][ix] = v;
        }
    }
    __syncthreads();

    float acc[COUT];
#pragma unroll
    for (int o = 0; o < COUT; ++o) acc[o] = bias[o];

#pragma unroll
    for (int c = 0; c < CIN; ++c) {
#pragma unroll
        for (int ky = 0; ky < 3; ++ky) {
#pragma unroll
            for (int kx = 0; kx < 3; ++kx) {
                float v = s_in[c][ty + ky][tx + kx];
#pragma unroll
                for (int o = 0; o < COUT; ++o)
                    acc[o] = fmaf(v, wgt[((o * CIN + c) * 3 + ky) * 3 + kx], acc[o]);
            }
        }
    }

    const int gy = y0 + ty, gx = x0 + tx;
    const size_t pix = (size_t)b * 1024 + gy * W + gx;
    float s2 = 0.f;
    float v[COUT];
#pragma unroll
    for (int o = 0; o < COUT; ++o) {
        v[o] = fmaxf(acc[o], 0.f);
        s2 = fmaf(v[o], v[o], s2);
    }
    float4* fq = (float4*)(ft + pix * 16);
    fq[0] = make_float4(v[0],  v[1],  v[2],  v[3]);
    fq[1] = make_float4(v[4],  v[5],  v[6],  v[7]);
    fq[2] = make_float4(v[8],  v[9],  v[10], v[11]);
    fq[3] = make_float4(v[12], v[13], v[14], v[15]);
    f2[pix] = s2;
}

// ---------------------------------------------------------------------------
// BoF: dist = f2 + c2 - 2 f.c (same expansion as reference). Features read
// with block-uniform addresses (-> scalar loads). Denominator via batched
// 512x16 LDS e-matrix column sum: 3 barriers per 16 pixels.
// Grid (8, B), block 512 (thread = codebook entry). partial: (B,8,512).
// ---------------------------------------------------------------------------
__global__ __launch_bounds__(512) void bof_kernel(
    const float* __restrict__ ft, const float* __restrict__ f2,
    const float* __restrict__ codebook, const float* __restrict__ sigma,
    float* __restrict__ partial)
{
    const int J = 16;
    const int b = blockIdx.y;
    const int chunk = blockIdx.x;
    const int t = threadIdx.x;

    __shared__ float s_e[KCB][J + 1];
    __shared__ float s_p[32][J + 1];
    __shared__ float s_dinv[J];

    float cb[DF];
    {
        const float4* cq = (const float4*)(codebook + (size_t)t * DF);
        float4 a0 = cq[0], a1 = cq[1], a2 = cq[2], a3 = cq[3];
        cb[0]=a0.x; cb[1]=a0.y; cb[2]=a0.z; cb[3]=a0.w;
        cb[4]=a1.x; cb[5]=a1.y; cb[6]=a1.z; cb[7]=a1.w;
        cb[8]=a2.x; cb[9]=a2.y; cb[10]=a2.z; cb[11]=a2.w;
        cb[12]=a3.x; cb[13]=a3.y; cb[14]=a3.z; cb[15]=a3.w;
    }
    float c2 = 0.f;
#pragma unroll
    for (int d = 0; d < DF; ++d) c2 = fmaf(cb[d], cb[d], c2);
    const float sg = sigma[t];

    const size_t base = (size_t)b * 1024 + chunk * 128;
    float acc = 0.f;

    for (int jb = 0; jb < 8; ++jb) {
        const int j0 = jb * J;
        float e[J];
#pragma unroll
        for (int jj = 0; jj < J; ++jj) {
            const float* fp = ft + (base + j0 + jj) * DF;  // uniform -> s_load
            float dot = 0.f;
#pragma unroll
            for (int d = 0; d < DF; ++d) dot = fmaf(fp[d], cb[d], dot);
            float f2c = f2[base + j0 + jj] + c2;           // uniform -> s_load
            float dist = fmaf(-2.f, dot, f2c);
            e[jj] = __expf(-dist * sg);
            s_e[t][jj] = e[jj];
        }
        __syncthreads();

        // column partial sums: 512 threads = 16 cols x 32 segments of 16 rows
        {
            const int c  = t & 15;
            const int sg2 = t >> 4;
            float ps = 0.f;
#pragma unroll
            for (int r = 0; r < 16; ++r) ps += s_e[sg2 * 16 + r][c];
            s_p[sg2][c] = ps;
        }
        __syncthreads();

        if (t < J) {
            float dsum = 0.f;
#pragma unroll
            for (int s2i = 0; s2i < 32; ++s2i) dsum += s_p[s2i][t];
            s_dinv[t] = 1.f / fmaxf(dsum, 1e-12f);
        }
        __syncthreads();

#pragma unroll
        for (int jj = 0; jj < J; ++jj)
            acc = fmaf(e[jj], s_dinv[jj], acc);
        // next batch's s_e writes are ordered after this batch's s_e reads by
        // the two barriers above; s_dinv reads race only with s_dinv writes
        // of the NEXT batch, which sit behind the next two barriers.
    }
    partial[((size_t)b * 8 + chunk) * KCB + t] = acc;
}

// ---------------------------------------------------------------------------
// Tail: pooled = sum(partial)/1024; z = relu(pooled @ l1w^T + b); out = z @ l2w^T + b
// Grid: B blocks x 512 threads.
// ---------------------------------------------------------------------------
__global__ __launch_bounds__(512) void tail_kernel(
    const float* __restrict__ partial,
    const float* __restrict__ l1w, const float* __restrict__ l1b,
    const float* __restrict__ l2w, const float* __restrict__ l2b,
    float* __restrict__ out)
{
    const int b = blockIdx.x;
    const int t = threadIdx.x;
    __shared__ float s_pool[KCB];
    __shared__ float s_z[20];

    float s = 0.f;
#pragma unroll
    for (int c = 0; c < 8; ++c)
        s += partial[((size_t)b * 8 + c) * KCB + t];
    s_pool[t] = s * (1.0f / 1024.0f);
    __syncthreads();

    if (t < 320) {
        const int row = t >> 4;
        const int l   = t & 15;
        float a = 0.f;
        const float* wr = l1w + (size_t)row * KCB;
#pragma unroll
        for (int m = 0; m < 32; ++m)
            a = fmaf(s_pool[l + 16 * m], wr[l + 16 * m], a);
#pragma unroll
        for (int off = 1; off < 16; off <<= 1)
            a += __shfl_xor(a, off);
        if (l == 0) s_z[row] = fmaxf(a + l1b[row], 0.f);
    }
    __syncthreads();

    if (t < 10) {
        float s2 = l2b[t];
#pragma unroll
        for (int j = 0; j < 20; ++j) s2 = fmaf(s_z[j], l2w[t * 20 + j], s2);
        out[b * 10 + t] = s2;
    }
}

// ---------------------------------------------------------------------------
extern "C" void kernel_launch(void* const* d_in, const int* in_sizes, int n_in,
                              void* d_out, int out_size, void* d_ws, size_t ws_size,
                              hipStream_t stream)
{
    const float* x        = (const float*)d_in[0];
    const float* w1       = (const float*)d_in[1];
    const float* b1       = (const float*)d_in[2];
    const float* w2       = (const float*)d_in[3];
    const float* b2       = (const float*)d_in[4];
    const float* w3       = (const float*)d_in[5];
    const float* b3       = (const float*)d_in[6];
    const float* w4       = (const float*)d_in[7];
    const float* b4       = (const float*)d_in[8];
    const float* codebook = (const float*)d_in[9];
    const float* sigma    = (const float*)d_in[10];
    const float* l1w      = (const float*)d_in[11];
    const float* l1b      = (const float*)d_in[12];
    const float* l2w      = (const float*)d_in[13];
    const float* l2b      = (const float*)d_in[14];
    float* out = (float*)d_out;

    float* ws = (float*)d_ws;
    const size_t N_C1 = (size_t)BATCH * 16 * 64 * 64;  // conv1 out
    const size_t N_P  = (size_t)BATCH * 16 * 32 * 32;  // conv2+pool out
    const size_t N_C3 = (size_t)BATCH * 24 * 32 * 32;  // conv3 out
    const size_t N_FT = (size_t)BATCH * 1024 * 16;     // transposed features
    const size_t N_F2 = (size_t)BATCH * 1024;          // feature sq-norms
    const size_t N_PART = (size_t)BATCH * 8 * KCB;

    float* c1   = ws;  ws += N_C1;
    float* p    = ws;  ws += N_P;
    float* c3   = ws;  ws += N_C3;
    float* ft   = ws;  ws += N_FT;
    float* f2   = ws;  ws += N_F2;
    float* part = ws;  ws += N_PART;

    // conv1: (B,3,64,64) -> (B,16,64,64)
    conv3x3_relu_kernel<3, 16, 16, 1><<<dim3(4, 4, BATCH), 256, 0, stream>>>(x, w1, b1, c1, 64, 64);
    // conv2 + maxpool: (B,16,64,64) -> (B,16,32,32)
    conv2_pool_kernel<<<dim3(4, 4, BATCH), 256, 0, stream>>>(c1, w2, b2, p);
    // conv3 (COUT split 2x12): (B,16,32,32) -> (B,24,32,32)
    conv3x3_relu_kernel<16, 12, 24, 2><<<dim3(2, 2, BATCH * 2), 256, 0, stream>>>(p, w3, b3, c3, 32, 32);
    // conv4 -> transposed features + norms
    conv4_ft_kernel<<<dim3(2, 2, BATCH), 256, 0, stream>>>(c3, w4, b4, ft, f2);
    // BoF membership + partial pooling
    bof_kernel<<<dim3(8, BATCH), 512, 0, stream>>>(ft, f2, codebook, sigma, part);
    // pooled mean + MLP head
    tail_kernel<<<BATCH, 512, 0, stream>>>(part, l1w, l1b, l2w, l2b, out);
}

// Round 4
// 198.606 us; speedup vs baseline: 1.3109x; 1.2531x over previous
//
#include <hip/hip_runtime.h>
#include <hip/hip_bf16.h>

#define KCB 512
#define DF  16
#define BATCH 64

// ---------------------------------------------------------------------------
// Generic 3x3 same conv + bias + relu, NCHW. COUT_T channels per block,
// NG channel-groups (blockIdx.z = b*NG + g). Each thread = one pixel.
// LDS rows padded to 19 to break stride-18 bank conflicts.
// ---------------------------------------------------------------------------
template<int CIN, int COUT_T, int COUT_TOTAL, int NG>
__global__ __launch_bounds__(256) void conv3x3_relu_kernel(
    const float* __restrict__ in, const float* __restrict__ wgt,
    const float* __restrict__ bias, float* __restrict__ out,
    int H, int W)
{
    __shared__ float s_in[CIN][18][19];
    const int zb = blockIdx.z;
    const int b  = zb / NG;
    const int og = (zb % NG) * COUT_T;
    const int x0 = blockIdx.x * 16;
    const int y0 = blockIdx.y * 16;
    const int tid = threadIdx.x;
    const int tx = tid & 15;
    const int ty = tid >> 4;

    for (int c = 0; c < CIN; ++c) {
        for (int i = tid; i < 18 * 18; i += 256) {
            int iy = i / 18, ix = i % 18;
            int gy = y0 + iy - 1, gx = x0 + ix - 1;
            float v = 0.f;
            if (gy >= 0 && gy < H && gx >= 0 && gx < W)
                v = in[((b * CIN + c) * H + gy) * W + gx];
            s_in[c][iy][ix] = v;
        }
    }
    __syncthreads();

    float acc[COUT_T];
#pragma unroll
    for (int o = 0; o < COUT_T; ++o) acc[o] = bias[og + o];

#pragma unroll
    for (int c = 0; c < CIN; ++c) {
#pragma unroll
        for (int ky = 0; ky < 3; ++ky) {
#pragma unroll
            for (int kx = 0; kx < 3; ++kx) {
                float v = s_in[c][ty + ky][tx + kx];
#pragma unroll
                for (int o = 0; o < COUT_T; ++o)
                    acc[o] = fmaf(v, wgt[(((og + o) * CIN + c) * 3 + ky) * 3 + kx], acc[o]);
            }
        }
    }

    const int gy = y0 + ty, gx = x0 + tx;
#pragma unroll
    for (int o = 0; o < COUT_T; ++o)
        out[((b * COUT_TOTAL + og + o) * H + gy) * W + gx] = fmaxf(acc[o], 0.f);
}

// ---------------------------------------------------------------------------
// conv2 (16->16, 64x64) fused with 2x2 maxpool, COUT split into NG=2 groups
// of 8. 2x2 max via shfl_xor(1)/(16) in-wave.
// ---------------------------------------------------------------------------
__global__ __launch_bounds__(256) void conv2_pool_kernel(
    const float* __restrict__ in, const float* __restrict__ wgt,
    const float* __restrict__ bias, float* __restrict__ out)
{
    const int CIN = 16, COUT_T = 8, H = 64, W = 64;
    __shared__ float s_in[16][18][19];
    const int zb = blockIdx.z;
    const int b  = zb >> 1;
    const int og = (zb & 1) * COUT_T;
    const int x0 = blockIdx.x * 16;
    const int y0 = blockIdx.y * 16;
    const int tid = threadIdx.x;
    const int tx = tid & 15;
    const int ty = tid >> 4;

    for (int c = 0; c < CIN; ++c) {
        for (int i = tid; i < 18 * 18; i += 256) {
            int iy = i / 18, ix = i % 18;
            int gy = y0 + iy - 1, gx = x0 + ix - 1;
            float v = 0.f;
            if (gy >= 0 && gy < H && gx >= 0 && gx < W)
                v = in[((b * CIN + c) * H + gy) * W + gx];
            s_in[c][iy][ix] = v;
        }
    }
    __syncthreads();

    float acc[COUT_T];
#pragma unroll
    for (int o = 0; o < COUT_T; ++o) acc[o] = bias[og + o];

#pragma unroll
    for (int c = 0; c < CIN; ++c) {
#pragma unroll
        for (int ky = 0; ky < 3; ++ky) {
#pragma unroll
            for (int kx = 0; kx < 3; ++kx) {
                float v = s_in[c][ty + ky][tx + kx];
#pragma unroll
                for (int o = 0; o < COUT_T; ++o)
                    acc[o] = fmaf(v, wgt[(((og + o) * CIN + c) * 3 + ky) * 3 + kx], acc[o]);
            }
        }
    }

    const bool writer = ((tx & 1) == 0) && ((ty & 1) == 0);
    const int px = (x0 + tx) >> 1;
    const int py = (y0 + ty) >> 1;
#pragma unroll
    for (int o = 0; o < COUT_T; ++o) {
        float r = fmaxf(acc[o], 0.f);
        r = fmaxf(r, __shfl_xor(r, 1));   // tx pair
        r = fmaxf(r, __shfl_xor(r, 16));  // ty pair (same wave)
        if (writer)
            out[((b * 16 + og + o) * 32 + py) * 32 + px] = r;
    }
}

// ---------------------------------------------------------------------------
// conv4 (24->16, 32x32), COUT split into 4 groups of 4. Each group writes its
// float4 slice of transposed features ft (B,1024,16) and a partial sq-norm
// f2p[g] (B*1024 each).
// ---------------------------------------------------------------------------
__global__ __launch_bounds__(256) void conv4_ft_kernel(
    const float* __restrict__ in, const float* __restrict__ wgt,
    const float* __restrict__ bias, float* __restrict__ ft,
    float* __restrict__ f2p)
{
    const int CIN = 24, COUT_T = 4, H = 32, W = 32;
    __shared__ float s_in[24][18][19];
    const int zb = blockIdx.z;
    const int b  = zb >> 2;
    const int g  = zb & 3;
    const int og = g * COUT_T;
    const int x0 = blockIdx.x * 16;
    const int y0 = blockIdx.y * 16;
    const int tid = threadIdx.x;
    const int tx = tid & 15;
    const int ty = tid >> 4;

    for (int c = 0; c < CIN; ++c) {
        for (int i = tid; i < 18 * 18; i += 256) {
            int iy = i / 18, ix = i % 18;
            int gy = y0 + iy - 1, gx = x0 + ix - 1;
            float v = 0.f;
            if (gy >= 0 && gy < H && gx >= 0 && gx < W)
                v = in[((b * CIN + c) * H + gy) * W + gx];
            s_in[c][iy][ix] = v;
        }
    }
    __syncthreads();

    float acc[COUT_T];
#pragma unroll
    for (int o = 0; o < COUT_T; ++o) acc[o] = bias[og + o];

#pragma unroll
    for (int c = 0; c < CIN; ++c) {
#pragma unroll
        for (int ky = 0; ky < 3; ++ky) {
#pragma unroll
            for (int kx = 0; kx < 3; ++kx) {
                float v = s_in[c][ty + ky][tx + kx];
#pragma unroll
                for (int o = 0; o < COUT_T; ++o)
                    acc[o] = fmaf(v, wgt[(((og + o) * CIN + c) * 3 + ky) * 3 + kx], acc[o]);
            }
        }
    }

    const int gy = y0 + ty, gx = x0 + tx;
    const size_t pix = (size_t)b * 1024 + gy * W + gx;
    float v0 = fmaxf(acc[0], 0.f), v1 = fmaxf(acc[1], 0.f);
    float v2 = fmaxf(acc[2], 0.f), v3 = fmaxf(acc[3], 0.f);
    *(float4*)(ft + pix * 16 + og) = make_float4(v0, v1, v2, v3);
    float s2 = v0 * v0;
    s2 = fmaf(v1, v1, s2);
    s2 = fmaf(v2, v2, s2);
    s2 = fmaf(v3, v3, s2);
    f2p[(size_t)g * (BATCH * 1024) + pix] = s2;
}

// ---------------------------------------------------------------------------
// BoF: dist = f2 + c2 - 2 f.c. Features read with block-uniform addresses
// (-> scalar loads). f2 partials summed once into LDS. Denominator via
// batched 512x16 LDS e-matrix column sum: 3 barriers per 16 pixels.
// Grid (8, B), block 512 (thread = codebook entry). partial: (B,8,512).
// ---------------------------------------------------------------------------
__global__ __launch_bounds__(512) void bof_kernel(
    const float* __restrict__ ft, const float* __restrict__ f2p,
    const float* __restrict__ codebook, const float* __restrict__ sigma,
    float* __restrict__ partial)
{
    const int J = 16;
    const int b = blockIdx.y;
    const int chunk = blockIdx.x;
    const int t = threadIdx.x;

    __shared__ float s_e[KCB][J + 1];
    __shared__ float s_p[32][J + 1];
    __shared__ float s_dinv[J];
    __shared__ float s_tmp[4][128];
    __shared__ float s_f2[128];

    const size_t base = (size_t)b * 1024 + chunk * 128;
    // stage f2 = sum of 4 conv4-group partials (coalesced: one load/thread)
    {
        const int g = t >> 7, j = t & 127;
        s_tmp[g][j] = f2p[(size_t)g * (BATCH * 1024) + base + j];
    }

    float cb[DF];
    {
        const float4* cq = (const float4*)(codebook + (size_t)t * DF);
        float4 a0 = cq[0], a1 = cq[1], a2 = cq[2], a3 = cq[3];
        cb[0]=a0.x; cb[1]=a0.y; cb[2]=a0.z; cb[3]=a0.w;
        cb[4]=a1.x; cb[5]=a1.y; cb[6]=a1.z; cb[7]=a1.w;
        cb[8]=a2.x; cb[9]=a2.y; cb[10]=a2.z; cb[11]=a2.w;
        cb[12]=a3.x; cb[13]=a3.y; cb[14]=a3.z; cb[15]=a3.w;
    }
    float c2 = 0.f;
#pragma unroll
    for (int d = 0; d < DF; ++d) c2 = fmaf(cb[d], cb[d], c2);
    const float sg = sigma[t];

    __syncthreads();
    if (t < 128) s_f2[t] = (s_tmp[0][t] + s_tmp[1][t]) + (s_tmp[2][t] + s_tmp[3][t]);
    __syncthreads();

    float acc = 0.f;

    for (int jb = 0; jb < 8; ++jb) {
        const int j0 = jb * J;
        float e[J];
#pragma unroll
        for (int jj = 0; jj < J; ++jj) {
            const float* fp = ft + (base + j0 + jj) * DF;  // uniform -> s_load
            float dot = 0.f;
#pragma unroll
            for (int d = 0; d < DF; ++d) dot = fmaf(fp[d], cb[d], dot);
            float f2c = s_f2[j0 + jj] + c2;                // LDS broadcast
            float dist = fmaf(-2.f, dot, f2c);
            e[jj] = __expf(-dist * sg);
            s_e[t][jj] = e[jj];
        }
        __syncthreads();

        // column partial sums: 512 threads = 16 cols x 32 segments of 16 rows
        {
            const int c  = t & 15;
            const int sg2 = t >> 4;
            float ps = 0.f;
#pragma unroll
            for (int r = 0; r < 16; ++r) ps += s_e[sg2 * 16 + r][c];
            s_p[sg2][c] = ps;
        }
        __syncthreads();

        if (t < J) {
            float dsum = 0.f;
#pragma unroll
            for (int s2i = 0; s2i < 32; ++s2i) dsum += s_p[s2i][t];
            s_dinv[t] = 1.f / fmaxf(dsum, 1e-12f);
        }
        __syncthreads();

#pragma unroll
        for (int jj = 0; jj < J; ++jj)
            acc = fmaf(e[jj], s_dinv[jj], acc);
    }
    partial[((size_t)b * 8 + chunk) * KCB + t] = acc;
}

// ---------------------------------------------------------------------------
// Tail: pooled = sum(partial)/1024; z = relu(pooled @ l1w^T + b); out = z @ l2w^T + b
// ---------------------------------------------------------------------------
__global__ __launch_bounds__(512) void tail_kernel(
    const float* __restrict__ partial,
    const float* __restrict__ l1w, const float* __restrict__ l1b,
    const float* __restrict__ l2w, const float* __restrict__ l2b,
    float* __restrict__ out)
{
    const int b = blockIdx.x;
    const int t = threadIdx.x;
    __shared__ float s_pool[KCB];
    __shared__ float s_z[20];

    float s = 0.f;
#pragma unroll
    for (int c = 0; c < 8; ++c)
        s += partial[((size_t)b * 8 + c) * KCB + t];
    s_pool[t] = s * (1.0f / 1024.0f);
    __syncthreads();

    if (t < 320) {
        const int row = t >> 4;
        const int l   = t & 15;
        float a = 0.f;
        const float* wr = l1w + (size_t)row * KCB;
#pragma unroll
        for (int m = 0; m < 32; ++m)
            a = fmaf(s_pool[l + 16 * m], wr[l + 16 * m], a);
#pragma unroll
        for (int off = 1; off < 16; off <<= 1)
            a += __shfl_xor(a, off);
        if (l == 0) s_z[row] = fmaxf(a + l1b[row], 0.f);
    }
    __syncthreads();

    if (t < 10) {
        float s2 = l2b[t];
#pragma unroll
        for (int j = 0; j < 20; ++j) s2 = fmaf(s_z[j], l2w[t * 20 + j], s2);
        out[b * 10 + t] = s2;
    }
}

// ---------------------------------------------------------------------------
extern "C" void kernel_launch(void* const* d_in, const int* in_sizes, int n_in,
                              void* d_out, int out_size, void* d_ws, size_t ws_size,
                              hipStream_t stream)
{
    const float* x        = (const float*)d_in[0];
    const float* w1       = (const float*)d_in[1];
    const float* b1       = (const float*)d_in[2];
    const float* w2       = (const float*)d_in[3];
    const float* b2       = (const float*)d_in[4];
    const float* w3       = (const float*)d_in[5];
    const float* b3       = (const float*)d_in[6];
    const float* w4       = (const float*)d_in[7];
    const float* b4       = (const float*)d_in[8];
    const float* codebook = (const float*)d_in[9];
    const float* sigma    = (const float*)d_in[10];
    const float* l1w      = (const float*)d_in[11];
    const float* l1b      = (const float*)d_in[12];
    const float* l2w      = (const float*)d_in[13];
    const float* l2b      = (const float*)d_in[14];
    float* out = (float*)d_out;

    float* ws = (float*)d_ws;
    const size_t N_C1 = (size_t)BATCH * 16 * 64 * 64;  // conv1 out
    const size_t N_P  = (size_t)BATCH * 16 * 32 * 32;  // conv2+pool out
    const size_t N_C3 = (size_t)BATCH * 24 * 32 * 32;  // conv3 out
    const size_t N_FT = (size_t)BATCH * 1024 * 16;     // transposed features
    const size_t N_F2 = (size_t)4 * BATCH * 1024;      // 4 partial sq-norms
    const size_t N_PART = (size_t)BATCH * 8 * KCB;

    float* c1   = ws;  ws += N_C1;
    float* p    = ws;  ws += N_P;
    float* c3   = ws;  ws += N_C3;
    float* ft   = ws;  ws += N_FT;
    float* f2p  = ws;  ws += N_F2;
    float* part = ws;  ws += N_PART;

    // conv1: (B,3,64,64) -> (B,16,64,64), 2 groups of 8
    conv3x3_relu_kernel<3, 8, 16, 2><<<dim3(4, 4, BATCH * 2), 256, 0, stream>>>(x, w1, b1, c1, 64, 64);
    // conv2 + maxpool: (B,16,64,64) -> (B,16,32,32), 2 groups of 8
    conv2_pool_kernel<<<dim3(4, 4, BATCH * 2), 256, 0, stream>>>(c1, w2, b2, p);
    // conv3: (B,16,32,32) -> (B,24,32,32), 4 groups of 6
    conv3x3_relu_kernel<16, 6, 24, 4><<<dim3(2, 2, BATCH * 4), 256, 0, stream>>>(p, w3, b3, c3, 32, 32);
    // conv4 -> transposed features + partial norms, 4 groups of 4
    conv4_ft_kernel<<<dim3(2, 2, BATCH * 4), 256, 0, stream>>>(c3, w4, b4, ft, f2p);
    // BoF membership + partial pooling
    bof_kernel<<<dim3(8, BATCH), 512, 0, stream>>>(ft, f2p, codebook, sigma, part);
    // pooled mean + MLP head
    tail_kernel<<<BATCH, 512, 0, stream>>>(part, l1w, l1b, l2w, l2b, out);
}